// Round 18
// baseline (453.113 us; speedup 1.0000x reference)
//
#include <hip/hip_runtime.h>
#include <math.h>

typedef unsigned int u32;
typedef unsigned char u8;
typedef long i64;
typedef float f32x16 __attribute__((ext_vector_type(16)));

static constexpr int N = 4096;         // B*L
static constexpr int D = 1024;
static constexpr int V = 32000;
static constexpr int K = 8;
static constexpr int BM = 128;         // q rows per block
static constexpr int BV = 256;         // vocab rows per block tile
static constexpr int BK = 128;         // k elems per stage (128 B fp8) -> 8 k-steps/tile
static constexpr int NTILES = V / BV;  // 125 vocab tiles of 256
static constexpr int NG = 16;          // vocab groups (7 or 8 tiles; cid < 2048)
static constexpr int NCAND = NG * K;   // 128 approx candidates per row
static constexpr int T24 = 24;         // rescored candidates per row
static constexpr int CPL = NCAND / 64; // 2 candidates per lane, exact
static constexpr int GRID = (N / BM) * NG;   // 512 = 2 blocks/CU (register-limited fit)
static constexpr u32 PSENT = 0x00800000u;    // packed(-3.4e38), unsigned-min sentinel

// d_out: [qn 4MB | vn 32.8MB | pad | cand @80MiB (2MB) | zero-tail @ZOFS .. N*V*4) [ids]
static constexpr size_t OUT_PROB_BYTES = (size_t)N * V * 4;            // 524,288,000
static constexpr size_t CAND_OFS = 83886080;                           // 80 MiB
static constexpr size_t ZOFS = CAND_OFS + (size_t)N * NCAND * 4;       // 85,983,232
static constexpr size_t NZ4 = (OUT_PROB_BYTES - ZOFS) / 16;            // 27,394,048 float4s
static constexpr size_t NQZ4 = CAND_OFS / 16;                          // 5,242,880 float4s
static constexpr int ZQUOTA = 208;                                     // 52 uniform 4-store steps
static constexpr size_t ZREM4 = NZ4 - (size_t)ZQUOTA * GRID * 256;     // 131,072 -> rescore

static_assert(N % BM == 0 && V % BV == 0, "tiling");
static_assert(ZOFS % 16 == 0, "align");
static_assert(ZQUOTA % 4 == 0 && ZQUOTA / 4 <= 56, "uniform 4-store steps fit min k-steps");
static_assert(ZREM4 == 131072 && ZREM4 <= (size_t)(N / 4) * 256, "rescore remainder fits");
static_assert(NQZ4 == (size_t)20 * (N / 4) * 256, "rescore zero quota exact");
static_assert((size_t)N * NCAND * 4 == (size_t)(N / 4) * 2048, "cand self-zero exact");

// float -> OCP e4m3 (RNE, clamp 448; subnormal below 2^-6). Filter-grade.
__device__ __forceinline__ u8 f2fp8(float f) {
  u32 u = __float_as_uint(f);
  u32 sign = (u >> 24) & 0x80u;
  u32 au = u & 0x7FFFFFFFu;
  if (au < 0x3D800000u) {                          // |f| < 2^-6: e4m3 subnormal (m*2^-9)
    int m = (int)(__uint_as_float(au) * 512.0f + 0.5f);
    return (u8)(sign | (u32)m);
  }
  au += 0x7FFFFu + ((au >> 20) & 1u);              // RNE to 3 mantissa bits
  if (au >= 0x43E00000u) return (u8)(sign | 0x7Eu);  // clamp to 448
  u32 e = (au >> 23) - 120u;                       // rebias 127 -> 7
  return (u8)(sign | (e << 3) | ((au >> 20) & 7u));
}
// monotone f32 -> sortable u32
__device__ __forceinline__ u32 flipbits(float v) {
  u32 u = __float_as_uint(v);
  return u ^ (((u32)((int)u >> 31)) | 0x80000000u);
}
// float upper bound of packed slot (11-bit cid field)
__device__ __forceinline__ float unpackval(u32 p) {
  u32 s = p | 2047u;
  u32 u = (s & 0x80000000u) ? (s ^ 0x80000000u) : ~s;
  return __uint_as_float(u);
}
// descending-sorted 8-slot insert, unsigned compare
__device__ __forceinline__ void insert8(u32 pv[K], u32 x) {
  if (x <= pv[K - 1]) return;
  bool g[K];
#pragma unroll
  for (int j = 0; j < K; ++j) g[j] = x > pv[j];
#pragma unroll
  for (int j = K - 1; j >= 1; --j)
    pv[j] = g[j - 1] ? pv[j - 1] : (g[j] ? x : pv[j]);
  if (g[0]) pv[0] = x;
}

// ---- fused: inverse L2 norm + normalized fp8 copy (x16) for BOTH inputs.
// Wave-per-row (4 rows/block), shfl-only reduce, no LDS/barrier. qn/vn and
// invq/invv are contiguous, so one global row index r in [0, N+V) serves both.
__global__ __launch_bounds__(256)
void normcvt_kernel(const float* __restrict__ emb, const float* __restrict__ vocab,
                    float* __restrict__ inv, u32* __restrict__ o) {
  const int gr = blockIdx.x * 4 + (threadIdx.x >> 6);
  const int l = threadIdx.x & 63;
  const float4* src = reinterpret_cast<const float4*>(
      gr < N ? emb + (size_t)gr * D : vocab + (size_t)(gr - N) * D);
  float4 v[4];
  float ss = 0.f;
#pragma unroll
  for (int j = 0; j < 4; ++j) {
    v[j] = src[j * 64 + l];
    ss += v[j].x * v[j].x + v[j].y * v[j].y + v[j].z * v[j].z + v[j].w * v[j].w;
  }
#pragma unroll
  for (int off = 32; off > 0; off >>= 1) ss += __shfl_xor(ss, off, 64);
  float iv = 1.0f / fmaxf(sqrtf(ss), 1e-12f);
  if (l == 0) inv[gr] = iv;
  float s = iv * 16.0f;                            // x16: stay in e4m3 normal range
#pragma unroll
  for (int j = 0; j < 4; ++j) {
    u32 p = (u32)f2fp8(v[j].x * s) | ((u32)f2fp8(v[j].y * s) << 8) |
            ((u32)f2fp8(v[j].z * s) << 16) | ((u32)f2fp8(v[j].w * s) << 24);
    o[(size_t)gr * (D / 4) + j * 64 + l] = p;
  }
}

// ------- fp8 MFMA sims (SWAPPED operands: A=vocab, B=query) + in-register top-8
// r15 structure with DE-DRAINED barriers: loads issued first, zero stores last
// (newest in vmcnt order); barrier1 = raw s_barrier (no vmem drain needed: all
// ds_reads are consumed pre-barrier via compiler lgkm waits); barrier2 = counted
// s_waitcnt vmcnt(4) + raw s_barrier -> all 12 staging loads complete while this
// step's 4 HBM stores stay in flight across the compute phase (T4: never drain
// to 0 mid-loop). Uniform 4-store quota (208 steps' worth; 2MiB rest in rescore).
__global__ __launch_bounds__(256, 2)
void simtopk_kernel(const u8* __restrict__ qn, const u8* __restrict__ vn,
                    u32* __restrict__ cand, float4* __restrict__ zout) {
  __shared__ __align__(16) u8 sh[(BV + BM) * BK]; // 48 KB: V tile | Q tile; merge alias

  const int tid = threadIdx.x;
  const int bid = blockIdx.x;
  // XCD-aware: XCD x (=bid&7) owns groups 2x,2x+1; rowblock fast-varying.
  const int u_ = bid >> 3;                         // 0..63
  const int rb = u_ & 31;                          // rowblock
  const int grp = (bid & 7) * 2 + (u_ >> 5);       // vocab group 0..15
  const int t0 = (grp * NTILES) >> 4;              // first vocab tile
  const int t1 = ((grp + 1) * NTILES) >> 4;        // past-last (t1-t0 = 7 or 8)
  const int rbase = rb * BM;
  const int wid = tid >> 6, l = tid & 63;
  const int wv = wid >> 1, wq = wid & 1;           // wave: vocab half x query half
  const int h = l >> 5, lid = l & 31;
  const int srow = l >> 3;                         // staging row within 8-row segment
  const int sk = ((l & 7) ^ srow) << 4;            // pre-swizzled src 16B-chunk offset
  const int csw = lid & 7;                         // frag-read swizzle (== row&7, all rows)

  // loop-invariant LDS byte offsets for the 6 fragment reads
  u32 vbase[4], qbase[2];
#pragma unroll
  for (int m = 0; m < 4; ++m) vbase[m] = (u32)((wv * 128 + m * 32 + lid) * BK);
#pragma unroll
  for (int n = 0; n < 2; ++n) qbase[n] = (u32)(BV * BK + (wq * 64 + n * 32 + lid) * BK);
  // strength-reduced staging bases (row term + swizzled chunk; tile/kk bumps added)
  const u8* vsb = vn + (size_t)(wid * 8 + srow) * D + sk;
  const u8* qsb = qn + (size_t)(rbase + wid * 8 + srow) * D + sk;
  const u32 ldst = (u32)(wid * 1024);              // LDS staging dest base (per wave)

  const float4 zf4 = make_float4(0.f, 0.f, 0.f, 0.f);
  float4* zcur = zout + (size_t)bid * 256 + tid;   // running zero-fill pointer
  int zrem = ZQUOTA;                               // uniform: 4 stores/step or none

  u32 pv[2][K];                                    // packed top-8 per owned q-row
#pragma unroll
  for (int n = 0; n < 2; ++n)
#pragma unroll
    for (int j = 0; j < K; ++j) pv[n][j] = PSENT;
  float tminf[2] = {-3.0e38f, -3.0e38f};

  for (int ti = t0; ti < t1; ++ti) {
    const int cb = (ti - t0) * BV;                 // local col base (packed cid space)
    const u8* vtile = vsb + (size_t)ti * BV * D;
    f32x16 acc[4][2];
#pragma unroll
    for (int m = 0; m < 4; ++m)
#pragma unroll
      for (int n = 0; n < 2; ++n)
#pragma unroll
        for (int r = 0; r < 16; ++r) acc[m][n][r] = 0.f;

    for (int kk = 0; kk < D / BK; ++kk) {          // 8 k-steps per tile
      // barrier1: staging area free. Raw barrier, NO vmem drain (each wave's
      // ds_reads were consumed before its last MFMA; stores ride through).
      __builtin_amdgcn_s_barrier();
      __builtin_amdgcn_sched_barrier(0);
      const u8* vk = vtile + kk * BK;
      const u8* qk = qsb + kk * BK;
      // stage vocab tile: 32 segments of 8 rows (8 calls/thread) -- FIRST
#pragma unroll
      for (int c = 0; c < 8; ++c) {
        __builtin_amdgcn_global_load_lds(
            (const __attribute__((address_space(1))) void*)(vk + (size_t)c * 32 * D),
            (__attribute__((address_space(3))) void*)(sh + ldst + c * 4096), 16, 0, 0);
      }
      // stage query tile: 16 segments (4 calls/thread)
#pragma unroll
      for (int c = 0; c < 4; ++c) {
        __builtin_amdgcn_global_load_lds(
            (const __attribute__((address_space(1))) void*)(qk + (size_t)c * 32 * D),
            (__attribute__((address_space(3))) void*)(sh + BV * BK + ldst + c * 4096), 16, 0, 0);
      }
      // fused zero-fill stores LAST (newest in vmcnt order) -> counted wait
      if (zrem > 0) {
#pragma unroll
        for (int j = 0; j < 4; ++j) { *zcur = zf4; zcur += GRID * 256; }
        zrem -= 4;
        asm volatile("s_waitcnt vmcnt(4)" ::: "memory");  // 12 loads done; 4 stores fly
      } else {
        asm volatile("s_waitcnt vmcnt(0)" ::: "memory");
      }
      __builtin_amdgcn_s_barrier();                // barrier2: LDS tile ready
      __builtin_amdgcn_sched_barrier(0);
      __builtin_amdgcn_s_setprio(1);
#pragma unroll
      for (int t = 0; t < 8; ++t) {                // 8 MFMA k-steps of 16 elems
        const u32 co = (u32)((((t ^ csw) << 4) | (h << 3)));  // shared by all 6 reads
        i64 vf[4], qf[2];
#pragma unroll
        for (int m = 0; m < 4; ++m)
          vf[m] = *reinterpret_cast<const i64*>(sh + vbase[m] + co);
#pragma unroll
        for (int n = 0; n < 2; ++n)
          qf[n] = *reinterpret_cast<const i64*>(sh + qbase[n] + co);
#pragma unroll
        for (int m = 0; m < 4; ++m)
#pragma unroll
          for (int n = 0; n < 2; ++n)
            acc[m][n] = __builtin_amdgcn_mfma_f32_32x32x16_fp8_fp8(vf[m], qf[n], acc[m][n], 0, 0, 0);
      }
      __builtin_amdgcn_s_setprio(0);
    }

    // ---- in-register scan: per n (owned q-row), 4x16 values with col ids from reg
#pragma unroll
    for (int n = 0; n < 2; ++n) {
#pragma unroll
      for (int m = 0; m < 4; ++m) {
        f32x16 a = acc[m][n];
        float x01 = fmaxf(a[0], a[1]),   x23 = fmaxf(a[2], a[3]);
        float x45 = fmaxf(a[4], a[5]),   x67 = fmaxf(a[6], a[7]);
        float x89 = fmaxf(a[8], a[9]),   xab = fmaxf(a[10], a[11]);
        float xcd = fmaxf(a[12], a[13]), xef = fmaxf(a[14], a[15]);
        float mx = fmaxf(fmaxf(fmaxf(x01, x23), fmaxf(x45, x67)),
                         fmaxf(fmaxf(x89, xab), fmaxf(xcd, xef)));
        if (mx > tminf[n]) {
          const int cidb = cb + wv * 128 + m * 32 + 4 * h;
#pragma unroll
          for (int r = 0; r < 16; ++r) {
            float v = a[r];
            if (v > tminf[n]) {
              int cid = cidb + (r & 3) + 8 * (r >> 2);
              u32 p = (flipbits(v) & 0xFFFFF800u) | (u32)(2047 - cid);
              insert8(pv[n], p);
            }
          }
          tminf[n] = unpackval(pv[n][K - 1]);
        }
      }
    }
  }

  // ---- merge 4 contributors (wv x h) per q-row -> per-group top-8
  __syncthreads();                                 // full drain (stores + loads) once
  u32* marr = (u32*)sh;                            // [128 rows][4 contrib][8] = 16 KB
#pragma unroll
  for (int n = 0; n < 2; ++n)
#pragma unroll
    for (int j = 0; j < K; ++j)
      marr[((wq * 64 + n * 32 + lid) * 4 + (wv * 2 + h)) * K + j] = pv[n][j];
  __syncthreads();
  if (tid < BM) {
    u32 fv[K];
#pragma unroll
    for (int j = 0; j < K; ++j) fv[j] = PSENT;
#pragma unroll
    for (int c4 = 0; c4 < 4; ++c4)
#pragma unroll
      for (int j = 0; j < K; ++j) insert8(fv, marr[(tid * 4 + c4) * K + j]);
#pragma unroll
    for (int j = 0; j < K; ++j)
      cand[(size_t)(rbase + tid) * NCAND + grp * K + j] = fv[j];
  }
}

// ------- approx top-24 merge + exact fp32 rescore + top-8 + softmax (1 wave/row)
// Also zero-fills the dead qn/vn scratch (20 float4/thread), the 2MiB zero-tail
// remainder, and its OWN 4 cand rows (after a barrier) -> no standalone zero pass.
__global__ __launch_bounds__(256)
void rescore_kernel(const u32* __restrict__ cand,
                    const float* __restrict__ emb, const float* __restrict__ vocab,
                    const float* __restrict__ invq, const float* __restrict__ invv,
                    float* __restrict__ res_p, int* __restrict__ res_i,
                    float4* __restrict__ zq, float4* __restrict__ candz,
                    float4* __restrict__ ztail2) {
  const int tid = threadIdx.x, wid = tid >> 6, l = tid & 63;
  const int row = blockIdx.x * 4 + wid;
  const float4 zf4 = make_float4(0.f, 0.f, 0.f, 0.f);

  // fire-and-forget zero of [0, CAND_OFS): 20 stores/thread + 2MiB tail remainder
  {
    size_t base = (size_t)blockIdx.x * 256 + tid;
#pragma unroll
    for (int i = 0; i < 20; ++i)
      zq[(size_t)i * ((N / 4) * 256) + base] = zf4;
    if (base < ZREM4) ztail2[base] = zf4;
  }

  float4 q[4];                                     // emb row: lane l holds float4s t*64+l
#pragma unroll
  for (int t = 0; t < 4; ++t)
    q[t] = *(reinterpret_cast<const float4*>(emb + (size_t)row * D) + t * 64 + l);
  float iqr = invq[row];

  u32 pl[CPL]; int li[CPL];                        // packed candidates + global ids
#pragma unroll
  for (int t = 0; t < CPL; ++t) {
    int e = l * CPL + t;                           // 64*2 == 128, no masking
    u32 p = cand[(size_t)row * NCAND + e];
    int grp = e >> 3;
    int tile0 = (grp * NTILES) >> 4;               // group's first vocab tile
    pl[t] = p;
    li[t] = tile0 * BV + 2047 - (int)(p & 2047u);
  }
  // all 4 waves' cand reads done -> zero this block's 4 cand rows (2 KB exact)
  __syncthreads();
  if (tid < 128) candz[(size_t)blockIdx.x * 128 + tid] = zf4;

  int cidx[T24];                                   // approx top-24 by iterative extraction
#pragma unroll
  for (int jr = 0; jr < T24; ++jr) {
    u32 bp = pl[0]; int bi = li[0];
#pragma unroll
    for (int t = 1; t < CPL; ++t)
      if (pl[t] > bp || (pl[t] == bp && li[t] < bi)) { bp = pl[t]; bi = li[t]; }
#pragma unroll
    for (int off = 32; off > 0; off >>= 1) {
      u32 op = (u32)__shfl_xor((int)bp, off, 64); int oi = __shfl_xor(bi, off, 64);
      if (op > bp || (op == bp && oi < bi)) { bp = op; bi = oi; }
    }
    cidx[jr] = bi;
#pragma unroll
    for (int t = 0; t < CPL; ++t) if (li[t] == bi) pl[t] = 0u;
  }

  float sv[T24];                                   // exact fp32 cosine for each candidate
#pragma unroll
  for (int jr = 0; jr < T24; ++jr) {
    int ix = cidx[jr];
    const float4* vr = reinterpret_cast<const float4*>(vocab + (size_t)ix * D);
    float s = 0.f;
#pragma unroll
    for (int t = 0; t < 4; ++t) {
      float4 vv = vr[t * 64 + l];
      s += q[t].x * vv.x + q[t].y * vv.y + q[t].z * vv.z + q[t].w * vv.w;
    }
#pragma unroll
    for (int off = 32; off > 0; off >>= 1) s += __shfl_xor(s, off, 64);
    sv[jr] = s * iqr * invv[ix];
  }

  float pvv[K]; int pii[K];                        // exact top-8, idx-asc on ties
#pragma unroll
  for (int r8 = 0; r8 < K; ++r8) {
    float bv = sv[0]; int bi = cidx[0];
#pragma unroll
    for (int jr = 1; jr < T24; ++jr)
      if (sv[jr] > bv || (sv[jr] == bv && cidx[jr] < bi)) { bv = sv[jr]; bi = cidx[jr]; }
    pvv[r8] = bv; pii[r8] = bi;
#pragma unroll
    for (int jr = 0; jr < T24; ++jr) if (cidx[jr] == bi) sv[jr] = -3.0e38f;
  }

  float m = pvv[0], sum = 0.f, e8[K];
#pragma unroll
  for (int j = 0; j < K; ++j) { e8[j] = expf(pvv[j] - m); sum += e8[j]; }
  float isum = 1.f / sum;
  if (l == 0) {
#pragma unroll
    for (int j = 0; j < K; ++j) {
      res_p[row * K + j] = e8[j] * isum;
      res_i[row * K + j] = pii[j];
    }
  }
}

// --------------------------------------------- final scatter into zeroed probs
__global__ void scatter_kernel(const float* __restrict__ res_p, const int* __restrict__ res_i,
                               float* __restrict__ out) {
  int row = blockIdx.x * blockDim.x + threadIdx.x;
#pragma unroll
  for (int j = 0; j < K; ++j) out[(size_t)row * V + res_i[row * K + j]] = res_p[row * K + j];
  out[(size_t)N * V + row] = (float)res_i[row * K];  // token id = exact argmax
}

extern "C" void kernel_launch(void* const* d_in, const int* in_sizes, int n_in,
                              void* d_out, int out_size, void* d_ws, size_t ws_size,
                              hipStream_t stream) {
  const float* emb   = (const float*)d_in[0];
  const float* vocab = (const float*)d_in[1];
  float* out = (float*)d_out;

  // scratch carved out of d_out (probs region; re-zeroed before scatter)
  u8* qn = (u8*)d_out;                                     // 4 MB normalized fp8 Q (x16)
  u8* vn = qn + (size_t)N * D;                             // 32.8 MB normalized fp8 V (x16)
  u32* cand = (u32*)((char*)d_out + CAND_OFS);             // 2 MB
  float4* ztail = (float4*)((char*)d_out + ZOFS);          // zero-fill target in simtopk
  float4* ztail2 = ztail + (size_t)ZQUOTA * GRID * 256;    // 2 MiB remainder (rescore)

  float* wsf   = (float*)d_ws;
  float* invq  = wsf;                                      // N  (contiguous with invv)
  float* invv  = wsf + N;                                  // V
  float* res_p = wsf + N + V;                              // N*K
  int*   res_i = (int*)(wsf + N + V + N * K);              // N*K

  normcvt_kernel<<<(N + V) / 4, 256, 0, stream>>>(emb, vocab, invq, (u32*)qn);
  simtopk_kernel<<<GRID, 256, 0, stream>>>(qn, vn, cand, ztail);
  rescore_kernel<<<N / 4, 256, 0, stream>>>(cand, emb, vocab, invq, invv, res_p, res_i,
                                            (float4*)d_out, (float4*)cand, ztail2);
  scatter_kernel<<<N / 256, 256, 0, stream>>>(res_p, res_i, out);
}

// Round 19
// 445.414 us; speedup vs baseline: 1.0173x; 1.0173x over previous
//
#include <hip/hip_runtime.h>
#include <math.h>

typedef unsigned int u32;
typedef unsigned char u8;
typedef long i64;
typedef float f32x16 __attribute__((ext_vector_type(16)));

static constexpr int N = 4096;         // B*L
static constexpr int D = 1024;
static constexpr int V = 32000;
static constexpr int K = 8;
static constexpr int BM = 128;         // q rows per block
static constexpr int BV = 256;         // vocab rows per block tile
static constexpr int BK = 128;         // k elems per stage (128 B fp8) -> 8 k-steps/tile
static constexpr int NTILES = V / BV;  // 125 vocab tiles of 256
static constexpr int NG = 16;          // vocab groups (7 or 8 tiles; cid < 2048)
static constexpr int NCAND = NG * K;   // 128 approx candidates per row
static constexpr int T24 = 24;         // rescored candidates per row
static constexpr int CPL = NCAND / 64; // 2 candidates per lane, exact
static constexpr int GRID = (N / BM) * NG;   // 512 = 2 blocks/CU (register-limited fit)
static constexpr u32 PSENT = 0x00800000u;    // packed(-3.4e38), unsigned-min sentinel

// d_out: [qn 4MB | vn 32.8MB | pad | cand @80MiB (2MB) | zero-tail @ZOFS .. N*V*4) [ids]
static constexpr size_t OUT_PROB_BYTES = (size_t)N * V * 4;            // 524,288,000
static constexpr size_t CAND_OFS = 83886080;                           // 80 MiB
static constexpr size_t ZOFS = CAND_OFS + (size_t)N * NCAND * 4;       // 85,983,232
static constexpr size_t NZ4 = (OUT_PROB_BYTES - ZOFS) / 16;            // 27,394,048 float4s
static constexpr size_t NQZ4 = CAND_OFS / 16;                          // 5,242,880 float4s

static_assert(N % BM == 0 && V % BV == 0, "tiling");
static_assert(ZOFS % 16 == 0, "align");
static_assert(NZ4 == (size_t)209 * GRID * 256, "zero quota exact");    // 209 <= 56*4 min stores
static_assert(NQZ4 == (size_t)20 * (N / 4) * 256, "rescore zero quota exact");
static_assert((size_t)N * NCAND * 4 == (size_t)(N / 4) * 2048, "cand self-zero exact");

// float -> OCP e4m3 (RNE, clamp 448; subnormal below 2^-6). Filter-grade.
__device__ __forceinline__ u8 f2fp8(float f) {
  u32 u = __float_as_uint(f);
  u32 sign = (u >> 24) & 0x80u;
  u32 au = u & 0x7FFFFFFFu;
  if (au < 0x3D800000u) {                          // |f| < 2^-6: e4m3 subnormal (m*2^-9)
    int m = (int)(__uint_as_float(au) * 512.0f + 0.5f);
    return (u8)(sign | (u32)m);
  }
  au += 0x7FFFFu + ((au >> 20) & 1u);              // RNE to 3 mantissa bits
  if (au >= 0x43E00000u) return (u8)(sign | 0x7Eu);  // clamp to 448
  u32 e = (au >> 23) - 120u;                       // rebias 127 -> 7
  return (u8)(sign | (e << 3) | ((au >> 20) & 7u));
}
// monotone f32 -> sortable u32
__device__ __forceinline__ u32 flipbits(float v) {
  u32 u = __float_as_uint(v);
  return u ^ (((u32)((int)u >> 31)) | 0x80000000u);
}
// float upper bound of packed slot (11-bit cid field)
__device__ __forceinline__ float unpackval(u32 p) {
  u32 s = p | 2047u;
  u32 u = (s & 0x80000000u) ? (s ^ 0x80000000u) : ~s;
  return __uint_as_float(u);
}
// descending-sorted 8-slot insert, unsigned compare
__device__ __forceinline__ void insert8(u32 pv[K], u32 x) {
  if (x <= pv[K - 1]) return;
  bool g[K];
#pragma unroll
  for (int j = 0; j < K; ++j) g[j] = x > pv[j];
#pragma unroll
  for (int j = K - 1; j >= 1; --j)
    pv[j] = g[j - 1] ? pv[j - 1] : (g[j] ? x : pv[j]);
  if (g[0]) pv[0] = x;
}

// ---- fused: inverse L2 norm + normalized fp8 copy (x16) for BOTH inputs.
// Wave-per-row (4 rows/block), shfl-only reduce, no LDS/barrier. qn/vn and
// invq/invv are contiguous, so one global row index r in [0, N+V) serves both.
__global__ __launch_bounds__(256)
void normcvt_kernel(const float* __restrict__ emb, const float* __restrict__ vocab,
                    float* __restrict__ inv, u32* __restrict__ o) {
  const int gr = blockIdx.x * 4 + (threadIdx.x >> 6);
  const int l = threadIdx.x & 63;
  const float4* src = reinterpret_cast<const float4*>(
      gr < N ? emb + (size_t)gr * D : vocab + (size_t)(gr - N) * D);
  float4 v[4];
  float ss = 0.f;
#pragma unroll
  for (int j = 0; j < 4; ++j) {
    v[j] = src[j * 64 + l];
    ss += v[j].x * v[j].x + v[j].y * v[j].y + v[j].z * v[j].z + v[j].w * v[j].w;
  }
#pragma unroll
  for (int off = 32; off > 0; off >>= 1) ss += __shfl_xor(ss, off, 64);
  float iv = 1.0f / fmaxf(sqrtf(ss), 1e-12f);
  if (l == 0) inv[gr] = iv;
  float s = iv * 16.0f;                            // x16: stay in e4m3 normal range
#pragma unroll
  for (int j = 0; j < 4; ++j) {
    u32 p = (u32)f2fp8(v[j].x * s) | ((u32)f2fp8(v[j].y * s) << 8) |
            ((u32)f2fp8(v[j].z * s) << 16) | ((u32)f2fp8(v[j].w * s) << 24);
    o[(size_t)gr * (D / 4) + j * 64 + l] = p;
  }
}

// ------- fp8 MFMA sims (SWAPPED operands: A=vocab, B=query) + in-register top-8
// Best measured structure (r11/r14/r15/r17): BK=128B (8 k-steps/tile), 48KB
// single buffer, 2 barriers/k-step, launch_bounds(256,2). Hoisted frag bases +
// shared per-t chunk offset. Frag-read swizzle phys[r][c]=glob[r][c^(r&7)] ->
// 4-way. Fused zero-fill of the probs tail, quota s<209.
__global__ __launch_bounds__(256, 2)
void simtopk_kernel(const u8* __restrict__ qn, const u8* __restrict__ vn,
                    u32* __restrict__ cand, float4* __restrict__ zout) {
  __shared__ __align__(16) u8 sh[(BV + BM) * BK]; // 48 KB: V tile | Q tile; merge alias

  const int tid = threadIdx.x;
  const int bid = blockIdx.x;
  // XCD-aware: XCD x (=bid&7) owns groups 2x,2x+1; rowblock fast-varying.
  const int u_ = bid >> 3;                         // 0..63
  const int rb = u_ & 31;                          // rowblock
  const int grp = (bid & 7) * 2 + (u_ >> 5);       // vocab group 0..15
  const int t0 = (grp * NTILES) >> 4;              // first vocab tile
  const int t1 = ((grp + 1) * NTILES) >> 4;        // past-last (t1-t0 = 7 or 8)
  const int rbase = rb * BM;
  const int wid = tid >> 6, l = tid & 63;
  const int wv = wid >> 1, wq = wid & 1;           // wave: vocab half x query half
  const int h = l >> 5, lid = l & 31;
  const int srow = l >> 3;                         // staging row within 8-row segment
  const int sk = ((l & 7) ^ srow) << 4;            // pre-swizzled src 16B-chunk offset
  const int csw = lid & 7;                         // frag-read swizzle (== row&7, all rows)

  // loop-invariant LDS byte offsets for the 6 fragment reads
  u32 vbase[4], qbase[2];
#pragma unroll
  for (int m = 0; m < 4; ++m) vbase[m] = (u32)((wv * 128 + m * 32 + lid) * BK);
#pragma unroll
  for (int n = 0; n < 2; ++n) qbase[n] = (u32)(BV * BK + (wq * 64 + n * 32 + lid) * BK);
  // strength-reduced staging bases (row term + swizzled chunk; tile/kk bumps added)
  const u8* vsb = vn + (size_t)(wid * 8 + srow) * D + sk;
  const u8* qsb = qn + (size_t)(rbase + wid * 8 + srow) * D + sk;
  const u32 ldst = (u32)(wid * 1024);              // LDS staging dest base (per wave)

  const float4 zf4 = make_float4(0.f, 0.f, 0.f, 0.f);
  float4* zcur = zout + (size_t)bid * 256 + tid;   // running zero-fill pointer
  int zrem = 209;

  u32 pv[2][K];                                    // packed top-8 per owned q-row
#pragma unroll
  for (int n = 0; n < 2; ++n)
#pragma unroll
    for (int j = 0; j < K; ++j) pv[n][j] = PSENT;
  float tminf[2] = {-3.0e38f, -3.0e38f};

  for (int ti = t0; ti < t1; ++ti) {
    const int cb = (ti - t0) * BV;                 // local col base (packed cid space)
    const u8* vtile = vsb + (size_t)ti * BV * D;
    f32x16 acc[4][2];
#pragma unroll
    for (int m = 0; m < 4; ++m)
#pragma unroll
      for (int n = 0; n < 2; ++n)
#pragma unroll
        for (int r = 0; r < 16; ++r) acc[m][n][r] = 0.f;

    for (int kk = 0; kk < D / BK; ++kk) {          // 8 k-steps per tile
      __syncthreads();                             // staging area free
      // fused zero-fill of probs tail (drained by next barrier)
#pragma unroll
      for (int j = 0; j < 4; ++j) {
        if (zrem > 0) { *zcur = zf4; zcur += GRID * 256; --zrem; }
      }
      const u8* vk = vtile + kk * BK;
      const u8* qk = qsb + kk * BK;
      // stage vocab tile: 32 segments of 8 rows (8 calls/thread)
#pragma unroll
      for (int c = 0; c < 8; ++c) {
        __builtin_amdgcn_global_load_lds(
            (const __attribute__((address_space(1))) void*)(vk + (size_t)c * 32 * D),
            (__attribute__((address_space(3))) void*)(sh + ldst + c * 4096), 16, 0, 0);
      }
      // stage query tile: 16 segments (4 calls/thread)
#pragma unroll
      for (int c = 0; c < 4; ++c) {
        __builtin_amdgcn_global_load_lds(
            (const __attribute__((address_space(1))) void*)(qk + (size_t)c * 32 * D),
            (__attribute__((address_space(3))) void*)(sh + BV * BK + ldst + c * 4096), 16, 0, 0);
      }
      __syncthreads();                             // drains vmcnt -> LDS ready
      __builtin_amdgcn_s_setprio(1);
#pragma unroll
      for (int t = 0; t < 8; ++t) {                // 8 MFMA k-steps of 16 elems
        const u32 co = (u32)((((t ^ csw) << 4) | (h << 3)));  // shared by all 6 reads
        i64 vf[4], qf[2];
#pragma unroll
        for (int m = 0; m < 4; ++m)
          vf[m] = *reinterpret_cast<const i64*>(sh + vbase[m] + co);
#pragma unroll
        for (int n = 0; n < 2; ++n)
          qf[n] = *reinterpret_cast<const i64*>(sh + qbase[n] + co);
#pragma unroll
        for (int m = 0; m < 4; ++m)
#pragma unroll
          for (int n = 0; n < 2; ++n)
            acc[m][n] = __builtin_amdgcn_mfma_f32_32x32x16_fp8_fp8(vf[m], qf[n], acc[m][n], 0, 0, 0);
      }
      __builtin_amdgcn_s_setprio(0);
    }

    // ---- in-register scan: per n (owned q-row), 4x16 values with col ids from reg
#pragma unroll
    for (int n = 0; n < 2; ++n) {
#pragma unroll
      for (int m = 0; m < 4; ++m) {
        f32x16 a = acc[m][n];
        float x01 = fmaxf(a[0], a[1]),   x23 = fmaxf(a[2], a[3]);
        float x45 = fmaxf(a[4], a[5]),   x67 = fmaxf(a[6], a[7]);
        float x89 = fmaxf(a[8], a[9]),   xab = fmaxf(a[10], a[11]);
        float xcd = fmaxf(a[12], a[13]), xef = fmaxf(a[14], a[15]);
        float mx = fmaxf(fmaxf(fmaxf(x01, x23), fmaxf(x45, x67)),
                         fmaxf(fmaxf(x89, xab), fmaxf(xcd, xef)));
        if (mx > tminf[n]) {
          const int cidb = cb + wv * 128 + m * 32 + 4 * h;
#pragma unroll
          for (int r = 0; r < 16; ++r) {
            float v = a[r];
            if (v > tminf[n]) {
              int cid = cidb + (r & 3) + 8 * (r >> 2);
              u32 p = (flipbits(v) & 0xFFFFF800u) | (u32)(2047 - cid);
              insert8(pv[n], p);
            }
          }
          tminf[n] = unpackval(pv[n][K - 1]);
        }
      }
    }
  }

  // ---- merge 4 contributors (wv x h) per q-row -> per-group top-8
  __syncthreads();
  u32* marr = (u32*)sh;                            // [128 rows][4 contrib][8] = 16 KB
#pragma unroll
  for (int n = 0; n < 2; ++n)
#pragma unroll
    for (int j = 0; j < K; ++j)
      marr[((wq * 64 + n * 32 + lid) * 4 + (wv * 2 + h)) * K + j] = pv[n][j];
  __syncthreads();
  if (tid < BM) {
    u32 fv[K];
#pragma unroll
    for (int j = 0; j < K; ++j) fv[j] = PSENT;
#pragma unroll
    for (int c4 = 0; c4 < 4; ++c4)
#pragma unroll
      for (int j = 0; j < K; ++j) insert8(fv, marr[(tid * 4 + c4) * K + j]);
#pragma unroll
    for (int j = 0; j < K; ++j)
      cand[(size_t)(rbase + tid) * NCAND + grp * K + j] = fv[j];
  }
}

// ------- approx top-24 merge + exact fp32 rescore + top-8 + softmax (1 wave/row)
// Also zero-fills the dead qn/vn scratch (20 float4/thread) and its OWN 4 cand
// rows (after a barrier) -> no standalone zero kernel needed.
__global__ __launch_bounds__(256)
void rescore_kernel(const u32* __restrict__ cand,
                    const float* __restrict__ emb, const float* __restrict__ vocab,
                    const float* __restrict__ invq, const float* __restrict__ invv,
                    float* __restrict__ res_p, int* __restrict__ res_i,
                    float4* __restrict__ zq, float4* __restrict__ candz) {
  const int tid = threadIdx.x, wid = tid >> 6, l = tid & 63;
  const int row = blockIdx.x * 4 + wid;
  const float4 zf4 = make_float4(0.f, 0.f, 0.f, 0.f);

  // fire-and-forget zero of [0, CAND_OFS): 20 stores/thread, coalesced
  {
    size_t base = (size_t)blockIdx.x * 256 + tid;
#pragma unroll
    for (int i = 0; i < 20; ++i)
      zq[(size_t)i * ((N / 4) * 256) + base] = zf4;
  }

  float4 q[4];                                     // emb row: lane l holds float4s t*64+l
#pragma unroll
  for (int t = 0; t < 4; ++t)
    q[t] = *(reinterpret_cast<const float4*>(emb + (size_t)row * D) + t * 64 + l);
  float iqr = invq[row];

  u32 pl[CPL]; int li[CPL];                        // packed candidates + global ids
#pragma unroll
  for (int t = 0; t < CPL; ++t) {
    int e = l * CPL + t;                           // 64*2 == 128, no masking
    u32 p = cand[(size_t)row * NCAND + e];
    int grp = e >> 3;
    int tile0 = (grp * NTILES) >> 4;               // group's first vocab tile
    pl[t] = p;
    li[t] = tile0 * BV + 2047 - (int)(p & 2047u);
  }
  // all 4 waves' cand reads done -> zero this block's 4 cand rows (2 KB exact)
  __syncthreads();
  if (tid < 128) candz[(size_t)blockIdx.x * 128 + tid] = zf4;

  int cidx[T24];                                   // approx top-24 by iterative extraction
#pragma unroll
  for (int jr = 0; jr < T24; ++jr) {
    u32 bp = pl[0]; int bi = li[0];
#pragma unroll
    for (int t = 1; t < CPL; ++t)
      if (pl[t] > bp || (pl[t] == bp && li[t] < bi)) { bp = pl[t]; bi = li[t]; }
#pragma unroll
    for (int off = 32; off > 0; off >>= 1) {
      u32 op = (u32)__shfl_xor((int)bp, off, 64); int oi = __shfl_xor(bi, off, 64);
      if (op > bp || (op == bp && oi < bi)) { bp = op; bi = oi; }
    }
    cidx[jr] = bi;
#pragma unroll
    for (int t = 0; t < CPL; ++t) if (li[t] == bi) pl[t] = 0u;
  }

  float sv[T24];                                   // exact fp32 cosine for each candidate
#pragma unroll
  for (int jr = 0; jr < T24; ++jr) {
    int ix = cidx[jr];
    const float4* vr = reinterpret_cast<const float4*>(vocab + (size_t)ix * D);
    float s = 0.f;
#pragma unroll
    for (int t = 0; t < 4; ++t) {
      float4 vv = vr[t * 64 + l];
      s += q[t].x * vv.x + q[t].y * vv.y + q[t].z * vv.z + q[t].w * vv.w;
    }
#pragma unroll
    for (int off = 32; off > 0; off >>= 1) s += __shfl_xor(s, off, 64);
    sv[jr] = s * iqr * invv[ix];
  }

  float pvv[K]; int pii[K];                        // exact top-8, idx-asc on ties
#pragma unroll
  for (int r8 = 0; r8 < K; ++r8) {
    float bv = sv[0]; int bi = cidx[0];
#pragma unroll
    for (int jr = 1; jr < T24; ++jr)
      if (sv[jr] > bv || (sv[jr] == bv && cidx[jr] < bi)) { bv = sv[jr]; bi = cidx[jr]; }
    pvv[r8] = bv; pii[r8] = bi;
#pragma unroll
    for (int jr = 0; jr < T24; ++jr) if (cidx[jr] == bi) sv[jr] = -3.0e38f;
  }

  float m = pvv[0], sum = 0.f, e8[K];
#pragma unroll
  for (int j = 0; j < K; ++j) { e8[j] = expf(pvv[j] - m); sum += e8[j]; }
  float isum = 1.f / sum;
  if (l == 0) {
#pragma unroll
    for (int j = 0; j < K; ++j) {
      res_p[row * K + j] = e8[j] * isum;
      res_i[row * K + j] = pii[j];
    }
  }
}

// --------------------------------------------- final scatter into zeroed probs
__global__ void scatter_kernel(const float* __restrict__ res_p, const int* __restrict__ res_i,
                               float* __restrict__ out) {
  int row = blockIdx.x * blockDim.x + threadIdx.x;
#pragma unroll
  for (int j = 0; j < K; ++j) out[(size_t)row * V + res_i[row * K + j]] = res_p[row * K + j];
  out[(size_t)N * V + row] = (float)res_i[row * K];  // token id = exact argmax
}

extern "C" void kernel_launch(void* const* d_in, const int* in_sizes, int n_in,
                              void* d_out, int out_size, void* d_ws, size_t ws_size,
                              hipStream_t stream) {
  const float* emb   = (const float*)d_in[0];
  const float* vocab = (const float*)d_in[1];
  float* out = (float*)d_out;

  // scratch carved out of d_out (probs region; re-zeroed before scatter)
  u8* qn = (u8*)d_out;                                     // 4 MB normalized fp8 Q (x16)
  u8* vn = qn + (size_t)N * D;                             // 32.8 MB normalized fp8 V (x16)
  u32* cand = (u32*)((char*)d_out + CAND_OFS);             // 2 MB
  float4* ztail = (float4*)((char*)d_out + ZOFS);          // zero-fill target in simtopk

  float* wsf   = (float*)d_ws;
  float* invq  = wsf;                                      // N  (contiguous with invv)
  float* invv  = wsf + N;                                  // V
  float* res_p = wsf + N + V;                              // N*K
  int*   res_i = (int*)(wsf + N + V + N * K);              // N*K

  normcvt_kernel<<<(N + V) / 4, 256, 0, stream>>>(emb, vocab, invq, (u32*)qn);
  simtopk_kernel<<<GRID, 256, 0, stream>>>(qn, vn, cand, ztail);
  rescore_kernel<<<N / 4, 256, 0, stream>>>(cand, emb, vocab, invq, invv, res_p, res_i,
                                            (float4*)d_out, (float4*)cand);
  scatter_kernel<<<N / 256, 256, 0, stream>>>(res_p, res_i, out);
}